// Round 6
// baseline (112.470 us; speedup 1.0000x reference)
//
#include <hip/hip_runtime.h>
#include <math.h>

// Chamfer loss, B=32, N=2048, 3 used components.
// R5: overhead-bound fix. d2 = K=16 GEMM with split-bf16 slots (R3/R4-verified
// algebra, absmax 0). All conversion hoisted into a prep kernel that writes
// padded 64 B/point fragments (K-chunks 2,3 = zeros -> no masking). Main
// kernel: frags straight from global (coalesced, L2-resident), each wave owns
// 32 rows x full m=2048 -> row minima finish in-register, fused sqrt-sum
// epilogue, one atomicAdd per block. No LDS staging, no barriers in the loop,
// no ws sentinel, no sum kernel, no atomicMin.

#define NPTS   2048
#define NBATCH 32
#define NSIDE  (NBATCH * NPTS)       // 65536 points per cloud
#define SLAB   (NSIDE * 4)           // uint4 elements per slot slab (4 MB)
#define EPSF   1e-16f
#define BIGF   3.4e38f

typedef short bf16x8 __attribute__((ext_vector_type(8)));
typedef float f32x4  __attribute__((ext_vector_type(4)));

__device__ __forceinline__ short f2b(float f) {          // fp32 -> bf16 RNE
    unsigned u = __float_as_uint(f);
    return (short)((u + 0x7FFFu + ((u >> 16) & 1u)) >> 16);
}
__device__ __forceinline__ float b2f(short h) {
    return __uint_as_float(((unsigned)(unsigned short)h) << 16);
}
__device__ __forceinline__ float min3f(float a, float b, float c) {
    return fminf(fminf(a, b), c);    // -> v_min3_f32
}

// ws layout (uint4 units): [0,SLAB) A-form of P ; [SLAB,2S) A-form of Q ;
// [2S,3S) B-form of Q ; [3S,4S) B-form of P.   16 MB total.
__global__ __launch_bounds__(256) void chamfer_prep(
    const float* __restrict__ P, const float* __restrict__ Q,
    uint4* __restrict__ ws)
{
    const int i    = blockIdx.x * 256 + threadIdx.x;   // 0..131071
    const int side = i >> 16;                          // 0 = P, 1 = Q
    const int pt   = i & (NSIDE - 1);

    float4 v = ((const float4*)(side ? Q : P))[pt];    // P base == p[0]
    const float cx = v.y, cy = v.z, cz = v.w;
    const short one = f2b(1.0f);

    float n2 = cx * cx + cy * cy + cz * cz;
    short n2h = f2b(n2); short n2l = f2b(n2 - b2f(n2h));
    float tx = -2.f * cx; short mhx = f2b(tx); short mlx = f2b(tx - b2f(mhx));
    float ty = -2.f * cy; short mhy = f2b(ty); short mly = f2b(ty - b2f(mhy));
    float tz = -2.f * cz; short mhz = f2b(tz); short mlz = f2b(tz - b2f(mhz));
    short qhx = f2b(cx), qlx = f2b(cx - b2f(qhx));
    short qhy = f2b(cy), qly = f2b(cy - b2f(qhy));
    short qhz = f2b(cz), qlz = f2b(cz - b2f(qhz));

    __align__(16) short a16[16] = { n2h, n2l, one, one,
                                    mhx, mhy, mhz, mhx, mhy, mhz,
                                    mlx, mly, mlz, mlx, mly, mlz };
    __align__(16) short b16[16] = { one, one, n2h, n2l,
                                    qhx, qhy, qhz, qlx, qly, qlz,
                                    qhx, qhy, qhz, qlx, qly, qlz };
    const uint4 z4 = {0u, 0u, 0u, 0u};

    uint4* A = ws + (size_t)side * SLAB + (size_t)pt * 4;
    A[0] = ((const uint4*)a16)[0];
    A[1] = ((const uint4*)a16)[1];
    A[2] = z4;
    A[3] = z4;
    uint4* B = ws + (size_t)(side ? 2 : 3) * SLAB + (size_t)pt * 4;
    B[0] = ((const uint4*)b16)[0];
    B[1] = ((const uint4*)b16)[1];
    B[2] = z4;
    B[3] = z4;
}

__global__ __launch_bounds__(256) void chamfer_main(
    const uint4* __restrict__ ws, float* __restrict__ out)
{
    __shared__ float rbuf[4];
    const int tid  = threadIdx.x;
    const int w    = tid >> 6;
    const int lane = tid & 63;
    const int l15  = lane & 15;
    const int kc   = lane >> 4;          // K-chunk 0..3 (2,3 read zeros)
    const int bi   = blockIdx.x;         // 0..15 : 128-row block
    const int b    = blockIdx.y;         // batch
    const int dir  = blockIdx.z;         // 0: rows=P cols=Q ; 1: reverse

    const uint4* Aslab = ws + (size_t)dir * SLAB;         // A_P or A_Q
    const uint4* Bslab = ws + (size_t)(dir ? 3 : 2) * SLAB; // B_P or B_Q
    const size_t pbase = (size_t)b * NPTS;

    // ---- A fragments: wave w owns rows [bi*128 + w*32, +32) = 2 tiles
    bf16x8 Af[2];
    #pragma unroll
    for (int t = 0; t < 2; ++t) {
        const int pt = bi * 128 + w * 32 + t * 16 + l15;
        Af[t] = *(const bf16x8*)&Aslab[(pbase + pt) * 4 + kc];
    }

    f32x4 rm0 = {BIGF, BIGF, BIGF, BIGF};
    f32x4 rm1 = {BIGF, BIGF, BIGF, BIGF};
    const f32x4 z = {0.f, 0.f, 0.f, 0.f};

    // ---- main loop: full m = 2048 in 128 col-tiles, 2 per iter
    #pragma unroll 2
    for (int j = 0; j < 128; j += 2) {
        bf16x8 B0 = *(const bf16x8*)&Bslab[(pbase + j * 16 + l15) * 4 + kc];
        bf16x8 B1 = *(const bf16x8*)&Bslab[(pbase + (j + 1) * 16 + l15) * 4 + kc];
        f32x4 c00 = __builtin_amdgcn_mfma_f32_16x16x32_bf16(Af[0], B0, z, 0, 0, 0);
        f32x4 c10 = __builtin_amdgcn_mfma_f32_16x16x32_bf16(Af[1], B0, z, 0, 0, 0);
        f32x4 c01 = __builtin_amdgcn_mfma_f32_16x16x32_bf16(Af[0], B1, z, 0, 0, 0);
        f32x4 c11 = __builtin_amdgcn_mfma_f32_16x16x32_bf16(Af[1], B1, z, 0, 0, 0);
        #pragma unroll
        for (int g = 0; g < 4; ++g) {
            rm0[g] = min3f(rm0[g], c00[g], c01[g]);
            rm1[g] = min3f(rm1[g], c10[g], c11[g]);
        }
    }

    // ---- epilogue: butterfly over col lanes -> every lane holds row mins;
    // rows for this lane-group: (lane>>4)*4 + g (C layout, verified).
    float s = 0.f;
    #pragma unroll
    for (int t = 0; t < 2; ++t) {
        #pragma unroll
        for (int g = 0; g < 4; ++g) {
            float v = t ? rm1[g] : rm0[g];
            v = fminf(v, __shfl_xor(v, 1));
            v = fminf(v, __shfl_xor(v, 2));
            v = fminf(v, __shfl_xor(v, 4));
            v = fminf(v, __shfl_xor(v, 8));
            s += sqrtf(fmaxf(v, 0.f) + EPSF);   // same value across l15 group
        }
    }
    // sum the 4 distinct kc-groups (rows 0-3/4-7/8-11/12-15 of each tile)
    s += __shfl_xor(s, 16);
    s += __shfl_xor(s, 32);

    if (lane == 0) rbuf[w] = s;
    __syncthreads();
    if (tid == 0)
        atomicAdd(out, 0.5f * ((rbuf[0] + rbuf[1]) + (rbuf[2] + rbuf[3])));
}

extern "C" void kernel_launch(void* const* d_in, const int* in_sizes, int n_in,
                              void* d_out, int out_size, void* d_ws, size_t ws_size,
                              hipStream_t stream) {
    const float* P = (const float*)d_in[0];   // p[0] = first 32*2048*4 floats
    const float* Q = (const float*)d_in[1];
    float* out = (float*)d_out;
    uint4* ws = (uint4*)d_ws;

    hipMemsetAsync(out, 0, sizeof(float), stream);

    chamfer_prep<<<dim3(512), 256, 0, stream>>>(P, Q, ws);

    dim3 grid(NPTS / 128, NBATCH, 2);         // 16 x 32 x 2 = 1024 blocks
    chamfer_main<<<grid, 256, 0, stream>>>(ws, out);
}

// Round 7
// 87.398 us; speedup vs baseline: 1.2869x; 1.2869x over previous
//
#include <hip/hip_runtime.h>
#include <math.h>

// Chamfer loss, B=32, N=2048, 3 used components.
// R6: 32x32x16 MFMA -- K=16 exactly matches the 16 split-bf16 slots (no
// wasted K-half), 1024 pairs per MFMA, each 16B/lane B-load feeds 32 cols.
// Slot algebra (R3-R5 verified, absmax 0): d2 = A(p) . B(q) with
//   A = [x2h,x2l,1,1, -2ph(xyz),-2ph(xyz), -2pl(xyz),-2pl(xyz)]
//   B = [1,1,y2h,y2l,  qh(xyz),  ql(xyz),   qh(xyz),  ql(xyz)]
// A/B share K-placement (lane>>5 = K-half on both sides) -> HW K-permutation
// cancels. C/D: col=lane&31, row=(reg&3)+8*(reg>>2)+4*(lane>>5) [verified].
// Depth-1 B prefetch hides L2 latency; 32B records; XCD-swizzled grid
// (bid&7 = batch%8) keeps each batch's slabs in one XCD's L2.

#define NPTS   2048
#define NBATCH 32
#define NSIDE  (NBATCH * NPTS)       // 65536 points per cloud
#define SLAB32 (NSIDE * 2)           // uint4 elements per slab (32 B/point)
#define EPSF   1e-16f
#define BIGF   3.4e38f

typedef short bf16x8  __attribute__((ext_vector_type(8)));
typedef float f32x16  __attribute__((ext_vector_type(16)));

__device__ __forceinline__ short f2b(float f) {          // fp32 -> bf16 RNE
    unsigned u = __float_as_uint(f);
    return (short)((u + 0x7FFFu + ((u >> 16) & 1u)) >> 16);
}
__device__ __forceinline__ float b2f(short h) {
    return __uint_as_float(((unsigned)(unsigned short)h) << 16);
}
__device__ __forceinline__ float min3f(float a, float b, float c) {
    return fminf(fminf(a, b), c);    // -> v_min3_f32
}

// ws layout (uint4): [0,S) A_P ; [S,2S) A_Q ; [2S,3S) B_Q ; [3S,4S) B_P.
__global__ __launch_bounds__(256) void chamfer_prep(
    const float* __restrict__ P, const float* __restrict__ Q,
    uint4* __restrict__ ws)
{
    const int i    = blockIdx.x * 256 + threadIdx.x;   // 0..131071
    const int side = i >> 16;                          // 0 = P, 1 = Q
    const int pt   = i & (NSIDE - 1);

    float4 v = ((const float4*)(side ? Q : P))[pt];    // P base == p[0]
    const float cx = v.y, cy = v.z, cz = v.w;
    const short one = f2b(1.0f);

    float n2 = cx * cx + cy * cy + cz * cz;
    short n2h = f2b(n2); short n2l = f2b(n2 - b2f(n2h));
    float tx = -2.f * cx; short mhx = f2b(tx); short mlx = f2b(tx - b2f(mhx));
    float ty = -2.f * cy; short mhy = f2b(ty); short mly = f2b(ty - b2f(mhy));
    float tz = -2.f * cz; short mhz = f2b(tz); short mlz = f2b(tz - b2f(mhz));
    short qhx = f2b(cx), qlx = f2b(cx - b2f(qhx));
    short qhy = f2b(cy), qly = f2b(cy - b2f(qhy));
    short qhz = f2b(cz), qlz = f2b(cz - b2f(qhz));

    __align__(16) short a16[16] = { n2h, n2l, one, one,
                                    mhx, mhy, mhz, mhx, mhy, mhz,
                                    mlx, mly, mlz, mlx, mly, mlz };
    __align__(16) short b16[16] = { one, one, n2h, n2l,
                                    qhx, qhy, qhz, qlx, qly, qlz,
                                    qhx, qhy, qhz, qlx, qly, qlz };

    uint4* A = ws + (size_t)side * SLAB32 + (size_t)pt * 2;
    A[0] = ((const uint4*)a16)[0];
    A[1] = ((const uint4*)a16)[1];
    uint4* B = ws + (size_t)(side ? 2 : 3) * SLAB32 + (size_t)pt * 2;
    B[0] = ((const uint4*)b16)[0];
    B[1] = ((const uint4*)b16)[1];
}

__global__ __launch_bounds__(256) void chamfer_main(
    const uint4* __restrict__ ws, float* __restrict__ out)
{
    __shared__ float rbuf[4];
    const int tid  = threadIdx.x;
    const int w    = tid >> 6;
    const int lane = tid & 63;
    const int l31  = lane & 31;
    const int kh   = lane >> 5;              // K-half 0/1 (same role in A & B)

    // XCD swizzle: bid&7 pins all blocks of a batch to one XCD group
    const int bid  = blockIdx.x;             // 0..1023
    const int b    = (bid & 7) + 8 * ((bid >> 3) & 3);
    const int rest = bid >> 5;               // 0..31
    const int dir  = rest & 1;               // 0: rows=P/cols=Q ; 1: reverse
    const int bi   = rest >> 1;              // 0..15 : 128-row block

    const uint4* Aslab = ws + (size_t)dir * SLAB32;
    const uint4* Bslab = ws + (size_t)(dir ? 3 : 2) * SLAB32;
    const size_t pbase = (size_t)b * NPTS;

    // ---- A fragment: wave w owns rows [bi*128 + w*32, +32), row = l31
    bf16x8 Af = *(const bf16x8*)&Aslab[(pbase + bi * 128 + w * 32 + l31) * 2 + kh];

    float rm[16];
    #pragma unroll
    for (int i = 0; i < 16; ++i) rm[i] = BIGF;

    const f32x16 z = {0.f,0.f,0.f,0.f, 0.f,0.f,0.f,0.f,
                      0.f,0.f,0.f,0.f, 0.f,0.f,0.f,0.f};

    // ---- main loop: 64 col-tiles of 32, pairs with depth-1 prefetch
    const uint4* Bp = &Bslab[(pbase + l31) * 2 + kh];   // tile t at +t*64
    bf16x8 cur0 = *(const bf16x8*)(Bp);
    bf16x8 cur1 = *(const bf16x8*)(Bp + 64);
    #pragma unroll 4
    for (int g = 0; g < 31; ++g) {
        const uint4* nb = Bp + (size_t)(2 * g + 2) * 64;
        bf16x8 n0 = *(const bf16x8*)(nb);
        bf16x8 n1 = *(const bf16x8*)(nb + 64);
        f32x16 c0 = __builtin_amdgcn_mfma_f32_32x32x16_bf16(Af, cur0, z, 0, 0, 0);
        f32x16 c1 = __builtin_amdgcn_mfma_f32_32x32x16_bf16(Af, cur1, z, 0, 0, 0);
        #pragma unroll
        for (int i = 0; i < 16; ++i) rm[i] = min3f(rm[i], c0[i], c1[i]);
        cur0 = n0; cur1 = n1;
    }
    {
        f32x16 c0 = __builtin_amdgcn_mfma_f32_32x32x16_bf16(Af, cur0, z, 0, 0, 0);
        f32x16 c1 = __builtin_amdgcn_mfma_f32_32x32x16_bf16(Af, cur1, z, 0, 0, 0);
        #pragma unroll
        for (int i = 0; i < 16; ++i) rm[i] = min3f(rm[i], c0[i], c1[i]);
    }

    // ---- epilogue: reduce over 32 col-lanes (per half-wave), fused sqrt-sum.
    // Half kh holds rows {(i&3)+8*(i>>2)+4*kh} -- halves cover disjoint rows.
    float s = 0.f;
    #pragma unroll
    for (int i = 0; i < 16; ++i) {
        float v = rm[i];
        v = fminf(v, __shfl_xor(v, 1));
        v = fminf(v, __shfl_xor(v, 2));
        v = fminf(v, __shfl_xor(v, 4));
        v = fminf(v, __shfl_xor(v, 8));
        v = fminf(v, __shfl_xor(v, 16));
        s += sqrtf(fmaxf(v, 0.f) + EPSF);
    }
    s += __shfl_xor(s, 32);                 // combine the two row-halves

    if (lane == 0) rbuf[w] = s;
    __syncthreads();
    if (tid == 0)
        atomicAdd(out, 0.5f * ((rbuf[0] + rbuf[1]) + (rbuf[2] + rbuf[3])));
}

extern "C" void kernel_launch(void* const* d_in, const int* in_sizes, int n_in,
                              void* d_out, int out_size, void* d_ws, size_t ws_size,
                              hipStream_t stream) {
    const float* P = (const float*)d_in[0];   // p[0] = first 32*2048*4 floats
    const float* Q = (const float*)d_in[1];
    float* out = (float*)d_out;
    uint4* ws = (uint4*)d_ws;

    hipMemsetAsync(out, 0, sizeof(float), stream);

    chamfer_prep<<<dim3(512), 256, 0, stream>>>(P, Q, ws);

    chamfer_main<<<dim3(1024), 256, 0, stream>>>(ws, out);
}